// Round 6
// baseline (148.669 us; speedup 1.0000x reference)
//
#include <hip/hip_runtime.h>
#include <hip/hip_bf16.h>
#include <cstdint>

#define L_DIM 4800
#define C_DIM 256
#define CONF_ELEMS ((size_t)2 * L_DIM * L_DIM)

typedef _Float16 f16x8 __attribute__((ext_vector_type(8)));
typedef float f32x4 __attribute__((ext_vector_type(4)));
typedef float f32x16 __attribute__((ext_vector_type(16)));

typedef const __attribute__((address_space(1))) uint32_t glb_u32;
typedef __attribute__((address_space(3))) uint32_t lds_u32;

// ws layout (bytes):
//   invsum  f32[19200]        @0         (1/rowsum | 1/colsum, by reduceA)
//   colmaxF u32[9600]         @76800     (by reduceB)
//   X region                  @115200:
//     pass A: partA f32[50][9600]   (slots 0..24 = row partials per tx, 25..49 = col partials per ty)
//     pass B: rowbest u64[25][9600] @115200 ; colbest u32[25][9600] @2035200
//   h0 f16 [2*4800*256]       @2995200   (f16 path only)
//   h1 f16 [2*4800*256]       @7910400   -> end 12825600
#define WS_F16_NEEDED 12825600

__global__ __launch_bounds__(256) void k_cvt2(const float* __restrict__ f0,
                                              const float* __restrict__ f1,
                                              _Float16* __restrict__ h0,
                                              _Float16* __restrict__ h1) {
    int b = blockIdx.x;
    const float* src = (b < 1200) ? f0 : f1;
    _Float16* dst = (b < 1200) ? h0 : h1;
    int i = (b < 1200 ? b : b - 1200) * 256 + threadIdx.x;
    const float4* s4 = (const float4*)src;
    float4 a = s4[(size_t)i * 2], c = s4[(size_t)i * 2 + 1];
    f16x8 h = { (_Float16)a.x, (_Float16)a.y, (_Float16)a.z, (_Float16)a.w,
                (_Float16)c.x, (_Float16)c.y, (_Float16)c.z, (_Float16)c.w };
    *(f16x8*)(dst + (size_t)i * 8) = h;
}

// invsum[i] = 1 / sum_k partA[(base+k)][j]   (rows: slots 0..24; cols: slots 25..49)
__global__ __launch_bounds__(256) void k_reduceA(const float* __restrict__ partA,
                                                 float* __restrict__ invsum) {
    int i = blockIdx.x * 256 + threadIdx.x;
    if (i >= 19200) return;
    int base = (i < 9600) ? 0 : 25;
    int j = (i < 9600) ? i : i - 9600;
    float s = 0.f;
#pragma unroll 5
    for (int k = 0; k < 25; ++k)
        s += partA[(size_t)(base + k) * 9600 + j];
    invsum[i] = 1.0f / s;
}

__global__ __launch_bounds__(256) void k_reduceB(const unsigned* __restrict__ colbest,
                                                 unsigned* __restrict__ colmaxF) {
    int i = blockIdx.x * 256 + threadIdx.x;
    if (i >= 9600) return;
    unsigned m = 0u;
#pragma unroll 5
    for (int k = 0; k < 25; ++k)
        m = max(m, colbest[(size_t)k * 9600 + i]);
    colmaxF[i] = m;
}

// 192x192 tile GEMM, BK=64, 4 waves (2x2), wave tile 96x96 = 3x3 frags of
// v_mfma_f32_32x32x16_f16 (2x MACs per fragment byte vs 16x16x32 -> halves
// LDS-port pressure per MFMA cycle; 1250 blocks -> 4x less per-block overhead).
// LDS: single-buffer [192 rows][8 chunks of 16B], slot kc holds k-chunk
// kc ^ (row&7) (T2 both-sides swizzle via pre-swizzled global source; 8
// consecutive lanes cover 8 distinct chunks -> 0 bank conflicts).
// Grid: 1250 = 25x25x2, bijective XCD decode (m204 formula, 1250%8!=0).
// Epilogue: NO global atomics -- per-block LDS reduce, plain stores.
// Frag layouts (32x32x16): A/B: row|col = lane&31, k = (lane>>5)*8 + [0..8).
// C/D: col = lane&31, row = (reg&3) + 8*(reg>>2) + 4*(lane>>5).
template<bool F16SRC, bool FINAL>
__global__ __launch_bounds__(256, 2) void k_gemm2(const void* __restrict__ srcA,
                                                  const void* __restrict__ srcB,
                                                  float* __restrict__ conf,
                                                  const float* __restrict__ invsum,
                                                  float* __restrict__ partA,
                                                  unsigned long long* __restrict__ rowbest,
                                                  unsigned* __restrict__ colbest) {
    // bijective XCD swizzle for nwg=1250: q=156, r=2
    const int orig = blockIdx.x;
    const int xcd  = orig & 7;
    const int q8   = 156, r8 = 2;
    const int t    = (xcd < r8 ? xcd * (q8 + 1) : r8 * (q8 + 1) + (xcd - r8) * q8) + (orig >> 3);
    const int n    = t / 625;
    const int rem  = t - n * 625;
    const int ty   = rem / 25;
    const int tx   = rem - ty * 25;
    const int l0   = ty * 192;
    const int s0   = tx * 192;

    __shared__ __align__(16) _Float16 As[192 * 64];
    __shared__ __align__(16) _Float16 Bs[192 * 64];
    __shared__ __align__(16) char redbuf[4608];
    __shared__ float ivr_lds[192];

    const int tid  = threadIdx.x;
    const int lane = tid & 63;
    const int w    = tid >> 6;
    const int wr   = w >> 1, wc = w & 1;
    const int l31  = lane & 31;
    const int hi   = lane >> 5;

    if constexpr (FINAL) {
        if (tid < 192) ivr_lds[tid] = invsum[n * L_DIM + l0 + tid];  // ordered by first barrier
    }

    f32x16 acc[3][3] = {};

    const _Float16* Ah = (const _Float16*)srcA + ((size_t)n * L_DIM + l0) * C_DIM;
    const _Float16* Bh = (const _Float16*)srcB + ((size_t)n * L_DIM + s0) * C_DIM;
    const float*    Af = (const float*)srcA + ((size_t)n * L_DIM + l0) * C_DIM;
    const float*    Bf = (const float*)srcB + ((size_t)n * L_DIM + s0) * C_DIM;

    for (int kt = 0; kt < 4; ++kt) {
        const int k0 = kt * 64;
        __syncthreads();   // previous compute's LDS reads done before overwrite
        if constexpr (F16SRC) {
#pragma unroll
            for (int i = 0; i < 6; ++i) {
                int c   = tid + i * 256;
                int row = c >> 3;
                int kc  = (c & 7) ^ (row & 7);    // pre-swizzled global source
                __builtin_amdgcn_global_load_lds(
                    (glb_u32*)(Ah + (size_t)row * C_DIM + k0 + kc * 8),
                    (lds_u32*)(As + (i * 256 + w * 64) * 8), 16, 0, 0);
                __builtin_amdgcn_global_load_lds(
                    (glb_u32*)(Bh + (size_t)row * C_DIM + k0 + kc * 8),
                    (lds_u32*)(Bs + (i * 256 + w * 64) * 8), 16, 0, 0);
            }
        } else {
#pragma unroll
            for (int i = 0; i < 6; ++i) {
                int c   = tid + i * 256;
                int row = c >> 3;
                int kc  = (c & 7) ^ (row & 7);
                const float* pa = Af + (size_t)row * C_DIM + k0 + kc * 8;
                const float* pb = Bf + (size_t)row * C_DIM + k0 + kc * 8;
                float4 a0 = ((const float4*)pa)[0], a1 = ((const float4*)pa)[1];
                float4 b0 = ((const float4*)pb)[0], b1 = ((const float4*)pb)[1];
                f16x8 ha = { (_Float16)a0.x, (_Float16)a0.y, (_Float16)a0.z, (_Float16)a0.w,
                             (_Float16)a1.x, (_Float16)a1.y, (_Float16)a1.z, (_Float16)a1.w };
                f16x8 hb = { (_Float16)b0.x, (_Float16)b0.y, (_Float16)b0.z, (_Float16)b0.w,
                             (_Float16)b1.x, (_Float16)b1.y, (_Float16)b1.z, (_Float16)b1.w };
                *(f16x8*)(As + (size_t)c * 8) = ha;
                *(f16x8*)(Bs + (size_t)c * 8) = hb;
            }
        }
        __syncthreads();   // staged loads drained (vmcnt(0)) before reads

#pragma unroll
        for (int ks = 0; ks < 4; ++ks) {
            f16x8 af[3], bf[3];
#pragma unroll
            for (int mi = 0; mi < 3; ++mi) {
                int row = wr * 96 + mi * 32 + l31;
                int ck  = (ks * 2 + hi) ^ (row & 7);
                af[mi] = *(const f16x8*)(As + row * 64 + ck * 8);
            }
#pragma unroll
            for (int ni = 0; ni < 3; ++ni) {
                int row = wc * 96 + ni * 32 + l31;
                int ck  = (ks * 2 + hi) ^ (row & 7);
                bf[ni] = *(const f16x8*)(Bs + row * 64 + ck * 8);
            }
#pragma unroll
            for (int mi = 0; mi < 3; ++mi)
#pragma unroll
                for (int ni = 0; ni < 3; ++ni)
                    acc[mi][ni] = __builtin_amdgcn_mfma_f32_32x32x16_f16(af[mi], bf[ni], acc[mi][ni], 0, 0, 0);
        }
    }

    const float SIM_SCALE = 0.0390625f;  // (1/sqrt(C))^2 / TEMPERATURE

    if constexpr (!FINAL) {
        // Pass A: per-block row/col partial sums of e = exp(sim)
        float* redR = (float*)redbuf;             // [wc][192]
        float* redC = (float*)(redbuf + 1536);    // [wr][192]
        float cp[3] = {0.f, 0.f, 0.f};
#pragma unroll
        for (int mi = 0; mi < 3; ++mi) {
#pragma unroll
            for (int reg = 0; reg < 16; ++reg) {
                float e0 = __expf(acc[mi][0][reg] * SIM_SCALE);
                float e1 = __expf(acc[mi][1][reg] * SIM_SCALE);
                float e2 = __expf(acc[mi][2][reg] * SIM_SCALE);
                cp[0] += e0; cp[1] += e1; cp[2] += e2;
                float rsum = e0 + e1 + e2;
                rsum += __shfl_xor(rsum, 1);
                rsum += __shfl_xor(rsum, 2);
                rsum += __shfl_xor(rsum, 4);
                rsum += __shfl_xor(rsum, 8);
                rsum += __shfl_xor(rsum, 16);
                if (l31 == 0) {
                    int rl = wr * 96 + mi * 32 + (reg & 3) + 8 * (reg >> 2) + 4 * hi;
                    redR[wc * 192 + rl] = rsum;
                }
            }
        }
#pragma unroll
        for (int ni = 0; ni < 3; ++ni) {
            float v = cp[ni];
            v += __shfl_xor(v, 32);
            if (hi == 0)
                redC[wr * 192 + wc * 96 + ni * 32 + l31] = v;
        }
        __syncthreads();
        if (tid < 192) {
            partA[(size_t)tx * 9600 + n * L_DIM + l0 + tid] = redR[tid] + redR[192 + tid];
            partA[(size_t)(25 + ty) * 9600 + n * L_DIM + s0 + tid] = redC[tid] + redC[192 + tid];
        }
    } else {
        // Pass B: conf = exp(2*sim)*invR*invC -> write; per-block best stores
        unsigned long long* redRB = (unsigned long long*)redbuf;   // [wc][192]
        unsigned* redCB = (unsigned*)(redbuf + 3072);              // [wr][192]
        const size_t base = (size_t)n * L_DIM * L_DIM;
        float ivC[3];
#pragma unroll
        for (int ni = 0; ni < 3; ++ni)
            ivC[ni] = invsum[9600 + n * L_DIM + s0 + wc * 96 + ni * 32 + l31];
        float cmx[3] = {0.f, 0.f, 0.f};
#pragma unroll
        for (int mi = 0; mi < 3; ++mi) {
#pragma unroll
            for (int reg = 0; reg < 16; ++reg) {
                const int rl   = wr * 96 + mi * 32 + (reg & 3) + 8 * (reg >> 2) + 4 * hi;
                const float ivR = ivr_lds[rl];
                const size_t rowoff = base + (size_t)(l0 + rl) * L_DIM;
                float bv = -1.f; int bc = 0;
#pragma unroll
                for (int ni = 0; ni < 3; ++ni) {
                    const int gcol = s0 + wc * 96 + ni * 32 + l31;
                    float cf = __expf(acc[mi][ni][reg] * (2.0f * SIM_SCALE)) * ivR * ivC[ni];
                    conf[rowoff + gcol] = cf;
                    cmx[ni] = fmaxf(cmx[ni], cf);
                    if (cf > bv) { bv = cf; bc = gcol; }
                }
                unsigned long long pack =
                    ((unsigned long long)__float_as_uint(bv) << 32) |
                    (unsigned long long)(0xFFFFFFFFu - (unsigned)bc);
#pragma unroll
                for (int d = 1; d < 32; d <<= 1) {
                    unsigned long long o = __shfl_xor(pack, d);
                    if (o > pack) pack = o;
                }
                if (l31 == 0)
                    redRB[wc * 192 + rl] = pack;
            }
        }
#pragma unroll
        for (int ni = 0; ni < 3; ++ni) {
            float v = cmx[ni];
            v = fmaxf(v, __shfl_xor(v, 32));
            if (hi == 0)
                redCB[wr * 192 + wc * 96 + ni * 32 + l31] = __float_as_uint(v);
        }
        __syncthreads();
        if (tid < 192) {
            unsigned long long p0 = redRB[tid], p1 = redRB[192 + tid];
            rowbest[(size_t)tx * 9600 + n * L_DIM + l0 + tid] = (p0 > p1) ? p0 : p1;
            colbest[(size_t)ty * 9600 + n * L_DIM + s0 + tid] = max(redCB[tid], redCB[192 + tid]);
        }
    }
}

__global__ __launch_bounds__(256) void k_match(const unsigned long long* __restrict__ rowbest,
                                               const unsigned* __restrict__ colmaxF,
                                               float* __restrict__ out) {
    int i = blockIdx.x * 256 + threadIdx.x;
    if (i >= 2 * L_DIM) return;
    unsigned long long p = 0ull;
#pragma unroll 5
    for (int k = 0; k < 25; ++k) {
        unsigned long long o = rowbest[(size_t)k * 9600 + i];
        if (o > p) p = o;
    }
    int n = i / L_DIM, l = i % L_DIM;
    float v = __uint_as_float((unsigned)(p >> 32));
    int cand = (int)(0xFFFFFFFFu - (unsigned)(p & 0xFFFFFFFFull));
    if (cand < 0 || cand >= L_DIM) cand = 0;
    int h0 = l / 80, w0 = l % 80;
    int h1 = cand / 80, w1 = cand % 80;
    bool bm0 = (h0 >= 2) && (h0 < 58) && (w0 >= 2) && (w0 < 78);
    bool bm1 = (h1 >= 2) && (h1 < 58) && (w1 >= 2) && (w1 < 78);
    float cm = __uint_as_float(colmaxF[n * L_DIM + cand]);
    bool mask = (v > 0.2f) && bm0 && bm1 && (v == cm);
    out[CONF_ELEMS + i]         = mask ? 1.0f : 0.0f;        // mask_v
    out[CONF_ELEMS + 9600 + i]  = mask ? (float)cand : 0.0f; // j_ids
    out[CONF_ELEMS + 19200 + i] = mask ? v : 0.0f;           // mconf
}

extern "C" void kernel_launch(void* const* d_in, const int* in_sizes, int n_in,
                              void* d_out, int out_size, void* d_ws, size_t ws_size,
                              hipStream_t stream) {
    const float* f0 = (const float*)d_in[0];
    const float* f1 = (const float*)d_in[1];
    float* out = (float*)d_out;

    float* invsum = (float*)d_ws;
    unsigned* colmaxF = (unsigned*)((char*)d_ws + 76800);
    float* partA = (float*)((char*)d_ws + 115200);
    unsigned long long* rowbest = (unsigned long long*)((char*)d_ws + 115200);
    unsigned* colbest = (unsigned*)((char*)d_ws + 2035200);
    _Float16* h0 = (_Float16*)((char*)d_ws + 2995200);
    _Float16* h1 = h0 + (size_t)2 * L_DIM * C_DIM;

    const bool usef16 = ws_size >= WS_F16_NEEDED;

    if (usef16) {
        k_cvt2<<<dim3(2400), 256, 0, stream>>>(f0, f1, h0, h1);
        k_gemm2<true, false><<<dim3(1250), 256, 0, stream>>>(
            h0, h1, out, invsum, partA, rowbest, colbest);
        k_reduceA<<<dim3(75), 256, 0, stream>>>(partA, invsum);
        k_gemm2<true, true><<<dim3(1250), 256, 0, stream>>>(
            h0, h1, out, invsum, partA, rowbest, colbest);
    } else {
        k_gemm2<false, false><<<dim3(1250), 256, 0, stream>>>(
            f0, f1, out, invsum, partA, rowbest, colbest);
        k_reduceA<<<dim3(75), 256, 0, stream>>>(partA, invsum);
        k_gemm2<false, true><<<dim3(1250), 256, 0, stream>>>(
            f0, f1, out, invsum, partA, rowbest, colbest);
    }
    k_reduceB<<<dim3(38), 256, 0, stream>>>(colbest, colmaxF);
    k_match<<<dim3(38), 256, 0, stream>>>(rowbest, colmaxF, out);
}